// Round 7
// baseline (595.361 us; speedup 1.0000x reference)
//
#include <hip/hip_runtime.h>

// B=4, C=256, H=W=64, O=256, K=3, PAD=2, DIL=2; offset conv: 18ch 3x3 p1 d1.
// R7: K-dimension REORDERED as k = cb*576 + n*64 + cl (cb: 4 blocks of 64
// channels, n: 9 taps, cl: channel-in-block). Each 64-k chunk = (cb, n, 64
// consecutive channels) -> trivial frag addressing (kl == cl), one (n,px)
// table lookup per thread per chunk, short8 built in regs -> 1 ds_write_b128
// per 8 samples, x staged once per cb (9-chunk reuse). Same trick for the
// offset conv (k = cb*576 + t*64 + cl, unrolled t -> compile-time taps).

typedef __attribute__((ext_vector_type(8))) short short8;
typedef __attribute__((ext_vector_type(4))) float floatx4;

__device__ inline unsigned short f2bf(float f) {  // RNE fp32 -> bf16 bits
  unsigned int u = __float_as_uint(f);
  u += 0x7fff + ((u >> 16) & 1);
  return (unsigned short)(u >> 16);
}
__device__ inline float bflo(unsigned int u) { return __uint_as_float(u << 16); }
__device__ inline float bfhi(unsigned int u) {
  return __uint_as_float(u & 0xffff0000u);
}

// ---------------------------------------------------------------------------
// prep. wfrag (deform): [ci=36][mt=16][kt=2][lane=64][j=8],
//   val = dw[o = mt*16+(lane&15)][c*9 + n], c = cb*64 + kt*32 + (lane>>4)*8+j,
//   cb = ci/9, n = ci%9.
// wfragA (offset, M padded to 32): [ci=36][kt=2][mt=2][lane=64][j=8],
//   val = (o<18) ? ow[o][c*9 + t] : 0, c = cb*64 + kt*32 + (lane>>4)*8+j,
//   cb = ci/9, t = ci%9.
// ---------------------------------------------------------------------------
__global__ __launch_bounds__(256) void prep_kernel(
    const float* __restrict__ dw, const float* __restrict__ ow,
    unsigned short* __restrict__ wfrag, unsigned short* __restrict__ wfragA) {
  int idx = blockIdx.x * 256 + threadIdx.x;
  if (idx < 73728) {
    int ci = idx >> 11;
    int mt = (idx >> 7) & 15;
    int kt = (idx >> 6) & 1;
    int lane = idx & 63;
    int cb = ci / 9, n = ci - cb * 9;
    int o = mt * 16 + (lane & 15);
    int cbase = cb * 64 + kt * 32 + (lane >> 4) * 8;
    short8 v;
#pragma unroll
    for (int j = 0; j < 8; ++j)
      v[j] = (short)f2bf(dw[o * 2304 + (cbase + j) * 9 + n]);
    *((short8*)wfrag + idx) = v;
  } else {
    int e = idx - 73728;
    if (e < 9216) {
      int ci = e >> 8;
      int kt = (e >> 7) & 1;
      int mt = (e >> 6) & 1;
      int lane = e & 63;
      int cb = ci / 9, t = ci - cb * 9;
      int o = mt * 16 + (lane & 15);
      int cbase = cb * 64 + kt * 32 + (lane >> 4) * 8;
      short8 v;
      if (o < 18) {
#pragma unroll
        for (int j = 0; j < 8; ++j)
          v[j] = (short)f2bf(ow[o * 2304 + (cbase + j) * 9 + t]);
      } else {
        v = (short8)0;
      }
      *((short8*)wfragA + e) = v;
    }
  }
}

// ---------------------------------------------------------------------------
// Offset conv via MFMA, c-split by 2 (grid z): block does cbs {2z, 2z+1},
// 9 t-chunks each (t unrolled -> compile-time taps). x staged once per cb as
// bf16 channel-pairs [plane=32][10 rows x 16]; B-frag = 4 direct ds_read_b32
// + shifts per k-step. atomicAdd fp32 partials (off_buf zeroed per launch).
// ---------------------------------------------------------------------------
__global__ __launch_bounds__(256) void offset_conv_mfma(
    const float* __restrict__ x, const unsigned short* __restrict__ wfragA,
    float* __restrict__ off_buf) {
  int tid = threadIdx.x;
  int b = blockIdx.y, tile = blockIdx.x, zc = blockIdx.z;
  int h0 = (tile >> 3) * 8, w0 = (tile & 7) * 8;
  int lane = tid & 63, wv = tid >> 6;

  __shared__ unsigned int s_xq[2][5120];  // [buf][plane*160 + ry*16 + rx]

  floatx4 acc[2];
  acc[0] = (floatx4)(0.f);
  acc[1] = (floatx4)(0.f);

  const float* xb = x + (size_t)b * 256 * 4096;

  // stage cb = 2*zc
  for (int e = tid; e < 5120; e += 256) {
    int pl = e / 160, pos = e - pl * 160;
    int ry = pos >> 4, rx = pos & 15;
    int gy = h0 - 1 + ry, gx = w0 - 1 + rx;
    bool ok = (rx < 10 && gy >= 0 && gy < 64 && gx >= 0 && gx < 64);
    const float* p0 = xb + (size_t)(zc * 128 + pl * 2) * 4096;
    float v0 = ok ? p0[gy * 64 + gx] : 0.f;
    float v1 = ok ? p0[4096 + gy * 64 + gx] : 0.f;
    s_xq[0][e] = (unsigned int)f2bf(v0) | ((unsigned int)f2bf(v1) << 16);
  }
  __syncthreads();

  int p = wv * 16 + (lane & 15);
  int ly = p >> 3, lx = p & 7;
  int kq = lane >> 4;
  const short8* wA = (const short8*)wfragA;

  float pr0[20], pr1[20];

  for (int cc = 0; cc < 2; ++cc) {
    int cb = zc * 2 + cc;
    const unsigned int* xq = s_xq[cc];
#pragma unroll
    for (int t = 0; t < 9; ++t) {
      int ci = cb * 9 + t;
      short8 aa[2][2];
#pragma unroll
      for (int kt = 0; kt < 2; ++kt)
#pragma unroll
        for (int mt = 0; mt < 2; ++mt)
          aa[kt][mt] = wA[((ci * 2 + kt) * 2 + mt) * 64 + lane];
      if (cc == 0 && t == 6) {  // prefetch cb+1 staging into regs
#pragma unroll
        for (int k = 0; k < 20; ++k) {
          int e = tid + k * 256;
          int pl = e / 160, pos = e - pl * 160;
          int ry = pos >> 4, rx = pos & 15;
          int gy = h0 - 1 + ry, gx = w0 - 1 + rx;
          bool ok = (rx < 10 && gy >= 0 && gy < 64 && gx >= 0 && gx < 64);
          pr0[k] = 0.f;
          pr1[k] = 0.f;
          if (ok) {
            const float* p0 = xb + (size_t)(zc * 128 + 64 + pl * 2) * 4096;
            pr0[k] = p0[gy * 64 + gx];
            pr1[k] = p0[4096 + gy * 64 + gx];
          }
        }
      }
      if (cc == 0 && t == 7) {  // commit to buf 1 (unread until cc==1)
#pragma unroll
        for (int k = 0; k < 20; ++k) {
          int e = tid + k * 256;
          s_xq[1][e] =
              (unsigned int)f2bf(pr0[k]) | ((unsigned int)f2bf(pr1[k]) << 16);
        }
      }
      int ty = t / 3, tx = t - ty * 3;  // compile-time (t unrolled)
      int pxo = (ly + ty) * 16 + (lx + tx);
#pragma unroll
      for (int kt = 0; kt < 2; ++kt) {
        const unsigned int* bp = xq + (kt * 16 + kq * 4) * 160 + pxo;
        unsigned int u0 = bp[0], u1 = bp[160], u2 = bp[320], u3 = bp[480];
        short8 bfr;
        bfr[0] = (short)(u0 & 0xffff);
        bfr[1] = (short)(u0 >> 16);
        bfr[2] = (short)(u1 & 0xffff);
        bfr[3] = (short)(u1 >> 16);
        bfr[4] = (short)(u2 & 0xffff);
        bfr[5] = (short)(u2 >> 16);
        bfr[6] = (short)(u3 & 0xffff);
        bfr[7] = (short)(u3 >> 16);
        acc[0] = __builtin_amdgcn_mfma_f32_16x16x32_bf16(aa[kt][0], bfr,
                                                         acc[0], 0, 0, 0);
        acc[1] = __builtin_amdgcn_mfma_f32_16x16x32_bf16(aa[kt][1], bfr,
                                                         acc[1], 0, 0, 0);
      }
    }
    __syncthreads();
  }

  // epilogue (R6-verified): atomic partial sums
  int quad = lane >> 4, col = lane & 15;
  int pp2 = wv * 16 + col;
  int hh = h0 + (pp2 >> 3), ww = w0 + (pp2 & 7);
#pragma unroll
  for (int mt = 0; mt < 2; ++mt)
#pragma unroll
    for (int r = 0; r < 4; ++r) {
      int o = mt * 16 + quad * 4 + r;
      if (o < 18)
        atomicAdd(&off_buf[(((size_t)b * 18 + o) * 64 + hh) * 64 + ww],
                  acc[mt][r]);
    }
}

// ---------------------------------------------------------------------------
// Deform sampler for one chunk (cb, n): thread = (oct = wave, px = lane).
// 8 consecutive cl = 4 pair-planes; 16 corner u32 reads -> short8 in regs ->
// one ds_write_b128 into colf (R3-verified B-frag layout, kl == cl).
// ---------------------------------------------------------------------------
__device__ __forceinline__ void sample_chunk(
    const unsigned int* __restrict__ xpcb, int n,
    unsigned short* __restrict__ colf, int oct, int px,
    const float (*sw4)[64][4], const int (*scoff)[64]) {
  float4 wq = *(const float4*)&sw4[n][px][0];
  const unsigned int* bp = xpcb + oct * 960 + scoff[n][px];
  unsigned int ua[4], ub[4], uc[4], ud[4];
#pragma unroll
  for (int q = 0; q < 4; ++q) {
    const unsigned int* pl = bp + q * 240;
    ua[q] = pl[0];
    ub[q] = pl[1];
    uc[q] = pl[16];
    ud[q] = pl[17];
  }
  short8 v8;
#pragma unroll
  for (int q = 0; q < 4; ++q) {
    float lo = wq.x * bflo(ua[q]) + wq.y * bflo(ub[q]) + wq.z * bflo(uc[q]) +
               wq.w * bflo(ud[q]);
    float hi = wq.x * bfhi(ua[q]) + wq.y * bfhi(ub[q]) + wq.z * bfhi(uc[q]) +
               wq.w * bfhi(ud[q]);
    v8[2 * q] = (short)(__float_as_uint(lo) >> 16);
    v8[2 * q + 1] = (short)(__float_as_uint(hi) >> 16);
  }
  int nt = px >> 4, kt = oct >> 2, qk = oct & 3;
  *(short8*)&colf[((nt * 2 + kt) * 64 + ((px & 15) | (qk << 4))) * 8] = v8;
}

// ---------------------------------------------------------------------------
// Fused bilinear sample + bf16 MFMA GEMM. 8x8 px tile, 256 o, 512 thr
// (8 waves). Chunks ordered (cb 0..3) x (n 0..8); x staged once per cb
// (dbuf, prefetch n==6 / commit n==7); colf dbuf; ONE barrier per chunk:
// MFMA(ci) || sample(ci+1). MFMA wave role (oq,nh) and epilogue = R5.
// ---------------------------------------------------------------------------
__global__ __launch_bounds__(512) void deform_kernel(
    const float* __restrict__ x, const float* __restrict__ off_buf,
    const float* __restrict__ obias, const unsigned short* __restrict__ wfrag,
    const float* __restrict__ bias, float* __restrict__ out) {
  int tid = threadIdx.x;
  int b = blockIdx.y, tile = blockIdx.x;
  int h0 = (tile >> 3) * 8, w0 = (tile & 7) * 8;
  int lane = tid & 63, wv = tid >> 6;
  int oq = wv >> 1, nh = wv & 1;
  int oct = wv;

  __shared__ unsigned int s_xp[2][7680];  // [buf][plane*240 + ry*16 + rx]
  __shared__ __align__(16) unsigned short s_colf[2][4096];
  __shared__ __align__(16) float s_w4[9][64][4];
  __shared__ int s_coff[9][64];

  // phase 0 (R6-verified): bias + clip fused; off_buf holds raw atomic sums.
  for (int e = tid; e < 576; e += 512) {
    int n = e >> 6, pe = e & 63;
    int hy = h0 + (pe >> 3), wx = w0 + (pe & 7);
    float dy =
        off_buf[(((size_t)b * 18 + 2 * n) * 64 + hy) * 64 + wx] + obias[2 * n];
    float dx = off_buf[(((size_t)b * 18 + 2 * n + 1) * 64 + hy) * 64 + wx] +
               obias[2 * n + 1];
    dy = fminf(fmaxf(dy, -1.f), 1.f);
    dx = fminf(fmaxf(dx, -1.f), 1.f);
    float fy = dy + (float)(hy - 2 + (n / 3) * 2);
    float fx = dx + (float)(wx - 2 + (n % 3) * 2);
    float y0f = floorf(fy), x0f = floorf(fx);
    float wy1 = fy - y0f, wx1 = fx - x0f;
    float wy0 = 1.f - wy1, wx0 = 1.f - wx1;
    s_coff[n][pe] = ((int)y0f - (h0 - 3)) * 16 + ((int)x0f - (w0 - 3));
    s_w4[n][pe][0] = wy0 * wx0;
    s_w4[n][pe][1] = wy0 * wx1;
    s_w4[n][pe][2] = wy1 * wx0;
    s_w4[n][pe][3] = wy1 * wx1;
  }

  const float* xb = x + (size_t)b * 256 * 4096;
  // stage cb0 -> xp[0] (element-parallel, coalesced in rx)
  for (int e = tid; e < 7680; e += 512) {
    int pl = e / 240, pos = e - pl * 240;
    int ry = pos >> 4, rx = pos & 15;
    int gy = h0 - 3 + ry, gx = w0 - 3 + rx;
    bool ok = (rx < 15 && gy >= 0 && gy < 64 && gx >= 0 && gx < 64);
    const float* p0 = xb + (size_t)(pl * 2) * 4096;
    float v0 = ok ? p0[gy * 64 + gx] : 0.f;
    float v1 = ok ? p0[4096 + gy * 64 + gx] : 0.f;
    s_xp[0][e] = (unsigned int)f2bf(v0) | ((unsigned int)f2bf(v1) << 16);
  }
  __syncthreads();

  // prologue: sample chunk 0 (cb0, n0) -> colf[0]
  sample_chunk(s_xp[0], 0, s_colf[0], oct, lane, s_w4, s_coff);
  __syncthreads();

  floatx4 acc[4][2];
#pragma unroll
  for (int i = 0; i < 4; ++i)
#pragma unroll
    for (int j = 0; j < 2; ++j) acc[i][j] = (floatx4)(0.f);

  float pr0[15], pr1[15];

  for (int cb = 0; cb < 4; ++cb) {
    for (int n = 0; n < 9; ++n) {
      int ci = cb * 9 + n;
      // A-frags for chunk ci (global/L2; consumed at MFMA below)
      short8 areg[2][4];
      const short8* wg = (const short8*)wfrag + (size_t)ci * 2048;
#pragma unroll
      for (int kt = 0; kt < 2; ++kt)
#pragma unroll
        for (int mi = 0; mi < 4; ++mi)
          areg[kt][mi] = wg[((oq * 4 + mi) * 2 + kt) * 64 + lane];

      // staging prefetch / commit for cb+1 (dbuf; commit phase n==7 is
      // barrier-separated from first read at phase n==8's sampling)
      if (n == 6 && cb < 3) {
#pragma unroll
        for (int k = 0; k < 15; ++k) {
          int e = tid + k * 512;
          int pl = e / 240, pos = e - pl * 240;
          int ry = pos >> 4, rx = pos & 15;
          int gy = h0 - 3 + ry, gx = w0 - 3 + rx;
          bool ok = (rx < 15 && gy >= 0 && gy < 64 && gx >= 0 && gx < 64);
          pr0[k] = 0.f;
          pr1[k] = 0.f;
          if (ok) {
            const float* p0 = xb + (size_t)((cb + 1) * 64 + pl * 2) * 4096;
            pr0[k] = p0[gy * 64 + gx];
            pr1[k] = p0[4096 + gy * 64 + gx];
          }
        }
      }
      if (n == 7 && cb < 3) {
#pragma unroll
        for (int k = 0; k < 15; ++k) {
          int e = tid + k * 512;
          s_xp[(cb + 1) & 1][e] =
              (unsigned int)f2bf(pr0[k]) | ((unsigned int)f2bf(pr1[k]) << 16);
        }
      }

      // sample chunk ci+1 -> colf[(ci+1)&1]
      if (ci + 1 < 36) {
        int nn = n + 1, cbn = cb;
        if (nn == 9) {
          nn = 0;
          cbn = cb + 1;
        }
        sample_chunk(s_xp[cbn & 1], nn, s_colf[(ci + 1) & 1], oct, lane, s_w4,
                     s_coff);
      }

      // MFMA chunk ci from colf[ci&1]
      const unsigned short* cf = s_colf[ci & 1];
#pragma unroll
      for (int kt = 0; kt < 2; ++kt) {
        short8 bfr[2];
#pragma unroll
        for (int tn = 0; tn < 2; ++tn)
          bfr[tn] =
              *(const short8*)&cf[(((nh * 2 + tn) * 2 + kt) * 64 + lane) * 8];
#pragma unroll
        for (int mi = 0; mi < 4; ++mi)
#pragma unroll
          for (int tn = 0; tn < 2; ++tn)
            acc[mi][tn] = __builtin_amdgcn_mfma_f32_16x16x32_bf16(
                areg[kt][mi], bfr[tn], acc[mi][tn], 0, 0, 0);
      }
      __syncthreads();
    }
  }

  // epilogue (R5-verified): C/D col=lane&15, row=quad*4+r
  int quad = lane >> 4, col = lane & 15;
#pragma unroll
  for (int mi = 0; mi < 4; ++mi)
#pragma unroll
    for (int tn = 0; tn < 2; ++tn) {
      int pxo = (nh * 2 + tn) * 16 + col;
      int h = h0 + (pxo >> 3), w = w0 + (pxo & 7);
#pragma unroll
      for (int r = 0; r < 4; ++r) {
        int o = oq * 64 + mi * 16 + quad * 4 + r;
        out[(((size_t)b * 256 + o) * 64 + h) * 64 + w] =
            acc[mi][tn][r] + bias[o];
      }
    }
}

extern "C" void kernel_launch(void* const* d_in, const int* in_sizes, int n_in,
                              void* d_out, int out_size, void* d_ws,
                              size_t ws_size, hipStream_t stream) {
  (void)in_sizes; (void)n_in; (void)out_size; (void)ws_size;
  const float* x        = (const float*)d_in[0];  // (4,256,64,64)
  const float* offset_w = (const float*)d_in[1];  // (18,256,3,3)
  const float* offset_b = (const float*)d_in[2];  // (18,)
  const float* deform_w = (const float*)d_in[3];  // (256,256,3,3)
  const float* deform_b = (const float*)d_in[4];  // (256,)
  float* out = (float*)d_out;

  float* off_buf = (float*)d_ws;                                // 294912 f
  unsigned short* wfrag = (unsigned short*)(off_buf + 294912);  // 589824 bf16
  unsigned short* wfragA = wfrag + 589824;                      // 73728 bf16

  hipMemsetAsync(off_buf, 0, 294912 * sizeof(float), stream);
  prep_kernel<<<324, 256, 0, stream>>>(deform_w, offset_w, wfrag, wfragA);
  offset_conv_mfma<<<dim3(64, 4, 2), 256, 0, stream>>>(x, wfragA, off_buf);
  deform_kernel<<<dim3(64, 4), 512, 0, stream>>>(x, off_buf, offset_b, wfrag,
                                                 deform_b, out);
  hipMemcpyAsync(out + 4194304, deform_w, 589824 * sizeof(float),
                 hipMemcpyDeviceToDevice, stream);
}

// Round 8
// 154.833 us; speedup vs baseline: 3.8452x; 3.8452x over previous
//
#include <hip/hip_runtime.h>

// B=4, C=256, H=W=64, O=256, K=3, PAD=2, DIL=2; offset conv: 18ch 3x3 p1 d1.
// R8: R7's deform kernel kept byte-identical (K reordered as k = cb*576 +
// n*64 + cl -> trivial frag addressing; deform ~15us). Offset conv rewritten
// WITHOUT the register-prefetch arrays that caused a 256-VGPR scratch-spill
// catastrophe in R7 (2.3 GB HBM spill traffic): single-buffered LDS staging,
// barrier-separated, A-frags loaded just-in-time in a rolled t-loop.

typedef __attribute__((ext_vector_type(8))) short short8;
typedef __attribute__((ext_vector_type(4))) float floatx4;

__device__ inline unsigned short f2bf(float f) {  // RNE fp32 -> bf16 bits
  unsigned int u = __float_as_uint(f);
  u += 0x7fff + ((u >> 16) & 1);
  return (unsigned short)(u >> 16);
}
__device__ inline float bflo(unsigned int u) { return __uint_as_float(u << 16); }
__device__ inline float bfhi(unsigned int u) {
  return __uint_as_float(u & 0xffff0000u);
}

// ---------------------------------------------------------------------------
// prep. wfrag (deform): [ci=36][mt=16][kt=2][lane=64][j=8],
//   val = dw[o = mt*16+(lane&15)][c*9 + n], c = cb*64 + kt*32 + (lane>>4)*8+j,
//   cb = ci/9, n = ci%9.
// wfragA (offset, M padded to 32): [ci=36][kt=2][mt=2][lane=64][j=8],
//   val = (o<18) ? ow[o][c*9 + t] : 0.
// ---------------------------------------------------------------------------
__global__ __launch_bounds__(256) void prep_kernel(
    const float* __restrict__ dw, const float* __restrict__ ow,
    unsigned short* __restrict__ wfrag, unsigned short* __restrict__ wfragA) {
  int idx = blockIdx.x * 256 + threadIdx.x;
  if (idx < 73728) {
    int ci = idx >> 11;
    int mt = (idx >> 7) & 15;
    int kt = (idx >> 6) & 1;
    int lane = idx & 63;
    int cb = ci / 9, n = ci - cb * 9;
    int o = mt * 16 + (lane & 15);
    int cbase = cb * 64 + kt * 32 + (lane >> 4) * 8;
    short8 v;
#pragma unroll
    for (int j = 0; j < 8; ++j)
      v[j] = (short)f2bf(dw[o * 2304 + (cbase + j) * 9 + n]);
    *((short8*)wfrag + idx) = v;
  } else {
    int e = idx - 73728;
    if (e < 9216) {
      int ci = e >> 8;
      int kt = (e >> 7) & 1;
      int mt = (e >> 6) & 1;
      int lane = e & 63;
      int cb = ci / 9, t = ci - cb * 9;
      int o = mt * 16 + (lane & 15);
      int cbase = cb * 64 + kt * 32 + (lane >> 4) * 8;
      short8 v;
      if (o < 18) {
#pragma unroll
        for (int j = 0; j < 8; ++j)
          v[j] = (short)f2bf(ow[o * 2304 + (cbase + j) * 9 + t]);
      } else {
        v = (short8)0;
      }
      *((short8*)wfragA + e) = v;
    }
  }
}

// ---------------------------------------------------------------------------
// Offset conv via MFMA, c-split by 2 (grid z): block does cbs {2z, 2z+1}.
// Single-buffer LDS staging (barrier-separated; no register prefetch, no
// spills). x staged per cb as bf16 channel-pairs [plane=32][10 rows x 16];
// B-frag = 4 direct ds_read_b32 + shifts per k-step; A-frags loaded JIT in a
// rolled t-loop. atomicAdd fp32 partials (off_buf zeroed per launch).
// ---------------------------------------------------------------------------
__global__ __launch_bounds__(256) void offset_conv_mfma(
    const float* __restrict__ x, const unsigned short* __restrict__ wfragA,
    float* __restrict__ off_buf) {
  int tid = threadIdx.x;
  int b = blockIdx.y, tile = blockIdx.x, zc = blockIdx.z;
  int h0 = (tile >> 3) * 8, w0 = (tile & 7) * 8;
  int lane = tid & 63, wv = tid >> 6;

  __shared__ unsigned int s_xq[5120];  // [plane*160 + ry*16 + rx]

  floatx4 acc[2];
  acc[0] = (floatx4)(0.f);
  acc[1] = (floatx4)(0.f);

  const float* xb = x + (size_t)b * 256 * 4096;

  int p = wv * 16 + (lane & 15);
  int ly = p >> 3, lx = p & 7;
  int kq = lane >> 4;
  const short8* wA = (const short8*)wfragA;

  for (int cc = 0; cc < 2; ++cc) {
    int cb = zc * 2 + cc;
    __syncthreads();  // WAR vs previous cb's reads
    for (int e = tid; e < 5120; e += 256) {
      int pl = e / 160, pos = e - pl * 160;
      int ry = pos >> 4, rx = pos & 15;
      int gy = h0 - 1 + ry, gx = w0 - 1 + rx;
      bool ok = (rx < 10 && gy >= 0 && gy < 64 && gx >= 0 && gx < 64);
      const float* p0 = xb + (size_t)(cb * 64 + pl * 2) * 4096;
      float v0 = ok ? p0[gy * 64 + gx] : 0.f;
      float v1 = ok ? p0[4096 + gy * 64 + gx] : 0.f;
      s_xq[e] = (unsigned int)f2bf(v0) | ((unsigned int)f2bf(v1) << 16);
    }
    __syncthreads();
    for (int t = 0; t < 9; ++t) {  // rolled: keeps register pressure low
      int ci = cb * 9 + t;
      int ty = t / 3, tx = t - ty * 3;
      int pxo = (ly + ty) * 16 + (lx + tx);
#pragma unroll
      for (int kt = 0; kt < 2; ++kt) {
        short8 a0 = wA[((ci * 2 + kt) * 2 + 0) * 64 + lane];
        short8 a1 = wA[((ci * 2 + kt) * 2 + 1) * 64 + lane];
        const unsigned int* bp = s_xq + (kt * 16 + kq * 4) * 160 + pxo;
        unsigned int u0 = bp[0], u1 = bp[160], u2 = bp[320], u3 = bp[480];
        short8 bfr;
        bfr[0] = (short)(u0 & 0xffff);
        bfr[1] = (short)(u0 >> 16);
        bfr[2] = (short)(u1 & 0xffff);
        bfr[3] = (short)(u1 >> 16);
        bfr[4] = (short)(u2 & 0xffff);
        bfr[5] = (short)(u2 >> 16);
        bfr[6] = (short)(u3 & 0xffff);
        bfr[7] = (short)(u3 >> 16);
        acc[0] =
            __builtin_amdgcn_mfma_f32_16x16x32_bf16(a0, bfr, acc[0], 0, 0, 0);
        acc[1] =
            __builtin_amdgcn_mfma_f32_16x16x32_bf16(a1, bfr, acc[1], 0, 0, 0);
      }
    }
  }

  // epilogue (R6-verified): atomic partial sums
  int quad = lane >> 4, col = lane & 15;
  int pp2 = wv * 16 + col;
  int hh = h0 + (pp2 >> 3), ww = w0 + (pp2 & 7);
#pragma unroll
  for (int mt = 0; mt < 2; ++mt)
#pragma unroll
    for (int r = 0; r < 4; ++r) {
      int o = mt * 16 + quad * 4 + r;
      if (o < 18)
        atomicAdd(&off_buf[(((size_t)b * 18 + o) * 64 + hh) * 64 + ww],
                  acc[mt][r]);
    }
}

// ---------------------------------------------------------------------------
// Deform sampler for one chunk (cb, n): thread = (oct = wave, px = lane).
// 8 consecutive cl = 4 pair-planes; 16 corner u32 reads -> short8 in regs ->
// one ds_write_b128 into colf (R3-verified B-frag layout, kl == cl).
// ---------------------------------------------------------------------------
__device__ __forceinline__ void sample_chunk(
    const unsigned int* __restrict__ xpcb, int n,
    unsigned short* __restrict__ colf, int oct, int px,
    const float (*sw4)[64][4], const int (*scoff)[64]) {
  float4 wq = *(const float4*)&sw4[n][px][0];
  const unsigned int* bp = xpcb + oct * 960 + scoff[n][px];
  unsigned int ua[4], ub[4], uc[4], ud[4];
#pragma unroll
  for (int q = 0; q < 4; ++q) {
    const unsigned int* pl = bp + q * 240;
    ua[q] = pl[0];
    ub[q] = pl[1];
    uc[q] = pl[16];
    ud[q] = pl[17];
  }
  short8 v8;
#pragma unroll
  for (int q = 0; q < 4; ++q) {
    float lo = wq.x * bflo(ua[q]) + wq.y * bflo(ub[q]) + wq.z * bflo(uc[q]) +
               wq.w * bflo(ud[q]);
    float hi = wq.x * bfhi(ua[q]) + wq.y * bfhi(ub[q]) + wq.z * bfhi(uc[q]) +
               wq.w * bfhi(ud[q]);
    v8[2 * q] = (short)(__float_as_uint(lo) >> 16);
    v8[2 * q + 1] = (short)(__float_as_uint(hi) >> 16);
  }
  int nt = px >> 4, kt = oct >> 2, qk = oct & 3;
  *(short8*)&colf[((nt * 2 + kt) * 64 + ((px & 15) | (qk << 4))) * 8] = v8;
}

// ---------------------------------------------------------------------------
// Fused bilinear sample + bf16 MFMA GEMM. 8x8 px tile, 256 o, 512 thr
// (8 waves). Chunks ordered (cb 0..3) x (n 0..8); x staged once per cb
// (dbuf, prefetch n==6 / commit n==7); colf dbuf; ONE barrier per chunk:
// MFMA(ci) || sample(ci+1). R7-verified, kept identical.
// ---------------------------------------------------------------------------
__global__ __launch_bounds__(512) void deform_kernel(
    const float* __restrict__ x, const float* __restrict__ off_buf,
    const float* __restrict__ obias, const unsigned short* __restrict__ wfrag,
    const float* __restrict__ bias, float* __restrict__ out) {
  int tid = threadIdx.x;
  int b = blockIdx.y, tile = blockIdx.x;
  int h0 = (tile >> 3) * 8, w0 = (tile & 7) * 8;
  int lane = tid & 63, wv = tid >> 6;
  int oq = wv >> 1, nh = wv & 1;
  int oct = wv;

  __shared__ unsigned int s_xp[2][7680];  // [buf][plane*240 + ry*16 + rx]
  __shared__ __align__(16) unsigned short s_colf[2][4096];
  __shared__ __align__(16) float s_w4[9][64][4];
  __shared__ int s_coff[9][64];

  // phase 0 (R6-verified): bias + clip fused; off_buf holds raw atomic sums.
  for (int e = tid; e < 576; e += 512) {
    int n = e >> 6, pe = e & 63;
    int hy = h0 + (pe >> 3), wx = w0 + (pe & 7);
    float dy =
        off_buf[(((size_t)b * 18 + 2 * n) * 64 + hy) * 64 + wx] + obias[2 * n];
    float dx = off_buf[(((size_t)b * 18 + 2 * n + 1) * 64 + hy) * 64 + wx] +
               obias[2 * n + 1];
    dy = fminf(fmaxf(dy, -1.f), 1.f);
    dx = fminf(fmaxf(dx, -1.f), 1.f);
    float fy = dy + (float)(hy - 2 + (n / 3) * 2);
    float fx = dx + (float)(wx - 2 + (n % 3) * 2);
    float y0f = floorf(fy), x0f = floorf(fx);
    float wy1 = fy - y0f, wx1 = fx - x0f;
    float wy0 = 1.f - wy1, wx0 = 1.f - wx1;
    s_coff[n][pe] = ((int)y0f - (h0 - 3)) * 16 + ((int)x0f - (w0 - 3));
    s_w4[n][pe][0] = wy0 * wx0;
    s_w4[n][pe][1] = wy0 * wx1;
    s_w4[n][pe][2] = wy1 * wx0;
    s_w4[n][pe][3] = wy1 * wx1;
  }

  const float* xb = x + (size_t)b * 256 * 4096;
  // stage cb0 -> xp[0] (element-parallel, coalesced in rx)
  for (int e = tid; e < 7680; e += 512) {
    int pl = e / 240, pos = e - pl * 240;
    int ry = pos >> 4, rx = pos & 15;
    int gy = h0 - 3 + ry, gx = w0 - 3 + rx;
    bool ok = (rx < 15 && gy >= 0 && gy < 64 && gx >= 0 && gx < 64);
    const float* p0 = xb + (size_t)(pl * 2) * 4096;
    float v0 = ok ? p0[gy * 64 + gx] : 0.f;
    float v1 = ok ? p0[4096 + gy * 64 + gx] : 0.f;
    s_xp[0][e] = (unsigned int)f2bf(v0) | ((unsigned int)f2bf(v1) << 16);
  }
  __syncthreads();

  // prologue: sample chunk 0 (cb0, n0) -> colf[0]
  sample_chunk(s_xp[0], 0, s_colf[0], oct, lane, s_w4, s_coff);
  __syncthreads();

  floatx4 acc[4][2];
#pragma unroll
  for (int i = 0; i < 4; ++i)
#pragma unroll
    for (int j = 0; j < 2; ++j) acc[i][j] = (floatx4)(0.f);

  float pr0[15], pr1[15];

  for (int cb = 0; cb < 4; ++cb) {
    for (int n = 0; n < 9; ++n) {
      int ci = cb * 9 + n;
      // A-frags for chunk ci (global/L2; consumed at MFMA below)
      short8 areg[2][4];
      const short8* wg = (const short8*)wfrag + (size_t)ci * 2048;
#pragma unroll
      for (int kt = 0; kt < 2; ++kt)
#pragma unroll
        for (int mi = 0; mi < 4; ++mi)
          areg[kt][mi] = wg[((oq * 4 + mi) * 2 + kt) * 64 + lane];

      // staging prefetch / commit for cb+1 (dbuf; commit phase n==7 is
      // barrier-separated from first read at phase n==8's sampling)
      if (n == 6 && cb < 3) {
#pragma unroll
        for (int k = 0; k < 15; ++k) {
          int e = tid + k * 512;
          int pl = e / 240, pos = e - pl * 240;
          int ry = pos >> 4, rx = pos & 15;
          int gy = h0 - 3 + ry, gx = w0 - 3 + rx;
          bool ok = (rx < 15 && gy >= 0 && gy < 64 && gx >= 0 && gx < 64);
          pr0[k] = 0.f;
          pr1[k] = 0.f;
          if (ok) {
            const float* p0 = xb + (size_t)((cb + 1) * 64 + pl * 2) * 4096;
            pr0[k] = p0[gy * 64 + gx];
            pr1[k] = p0[4096 + gy * 64 + gx];
          }
        }
      }
      if (n == 7 && cb < 3) {
#pragma unroll
        for (int k = 0; k < 15; ++k) {
          int e = tid + k * 512;
          s_xp[(cb + 1) & 1][e] =
              (unsigned int)f2bf(pr0[k]) | ((unsigned int)f2bf(pr1[k]) << 16);
        }
      }

      // sample chunk ci+1 -> colf[(ci+1)&1]
      if (ci + 1 < 36) {
        int nn = n + 1, cbn = cb;
        if (nn == 9) {
          nn = 0;
          cbn = cb + 1;
        }
        sample_chunk(s_xp[cbn & 1], nn, s_colf[(ci + 1) & 1], oct, lane, s_w4,
                     s_coff);
      }

      // MFMA chunk ci from colf[ci&1]
      const unsigned short* cf = s_colf[ci & 1];
#pragma unroll
      for (int kt = 0; kt < 2; ++kt) {
        short8 bfr[2];
#pragma unroll
        for (int tn = 0; tn < 2; ++tn)
          bfr[tn] =
              *(const short8*)&cf[(((nh * 2 + tn) * 2 + kt) * 64 + lane) * 8];
#pragma unroll
        for (int mi = 0; mi < 4; ++mi)
#pragma unroll
          for (int tn = 0; tn < 2; ++tn)
            acc[mi][tn] = __builtin_amdgcn_mfma_f32_16x16x32_bf16(
                areg[kt][mi], bfr[tn], acc[mi][tn], 0, 0, 0);
      }
      __syncthreads();
    }
  }

  // epilogue (R5-verified): C/D col=lane&15, row=quad*4+r
  int quad = lane >> 4, col = lane & 15;
#pragma unroll
  for (int mi = 0; mi < 4; ++mi)
#pragma unroll
    for (int tn = 0; tn < 2; ++tn) {
      int pxo = (nh * 2 + tn) * 16 + col;
      int h = h0 + (pxo >> 3), w = w0 + (pxo & 7);
#pragma unroll
      for (int r = 0; r < 4; ++r) {
        int o = oq * 64 + mi * 16 + quad * 4 + r;
        out[(((size_t)b * 256 + o) * 64 + h) * 64 + w] =
            acc[mi][tn][r] + bias[o];
      }
    }
}

extern "C" void kernel_launch(void* const* d_in, const int* in_sizes, int n_in,
                              void* d_out, int out_size, void* d_ws,
                              size_t ws_size, hipStream_t stream) {
  (void)in_sizes; (void)n_in; (void)out_size; (void)ws_size;
  const float* x        = (const float*)d_in[0];  // (4,256,64,64)
  const float* offset_w = (const float*)d_in[1];  // (18,256,3,3)
  const float* offset_b = (const float*)d_in[2];  // (18,)
  const float* deform_w = (const float*)d_in[3];  // (256,256,3,3)
  const float* deform_b = (const float*)d_in[4];  // (256,)
  float* out = (float*)d_out;

  float* off_buf = (float*)d_ws;                                // 294912 f
  unsigned short* wfrag = (unsigned short*)(off_buf + 294912);  // 589824 bf16
  unsigned short* wfragA = wfrag + 589824;                      // 73728 bf16

  hipMemsetAsync(off_buf, 0, 294912 * sizeof(float), stream);
  prep_kernel<<<324, 256, 0, stream>>>(deform_w, offset_w, wfrag, wfragA);
  offset_conv_mfma<<<dim3(64, 4, 2), 256, 0, stream>>>(x, wfragA, off_buf);
  deform_kernel<<<dim3(64, 4), 512, 0, stream>>>(x, off_buf, offset_b, wfrag,
                                                 deform_b, out);
  hipMemcpyAsync(out + 4194304, deform_w, 589824 * sizeof(float),
                 hipMemcpyDeviceToDevice, stream);
}